// Round 1
// baseline (223.815 us; speedup 1.0000x reference)
//
#include <hip/hip_runtime.h>
#include <hip/hip_bf16.h>

// out[i, j] = x[i, j] * weight[j]
// x: 32768 x 1024 fp32, weight: 1024 fp32, out: 32768 x 1024 fp32.
// Memory-bound: 268 MB of HBM traffic, floor ~43 us at 6.3 TB/s.
// Strategy: one float4 per thread, flat index; column-of-float4 index is
// (idx & 255) since 1024/4 = 256 float4 per row. Weight (4 KiB) is served
// from L1/L2 after first touch.

__global__ __launch_bounds__(256) void diag_scale_kernel(
    const float4* __restrict__ x4,
    const float4* __restrict__ w4,   // 256 float4 = 1024 floats
    float4* __restrict__ out4,
    int n4)                          // total float4 count = 8388608
{
    int idx = blockIdx.x * blockDim.x + threadIdx.x;
    if (idx < n4) {
        float4 xv = x4[idx];
        float4 wv = w4[idx & 255];
        float4 ov;
        ov.x = xv.x * wv.x;
        ov.y = xv.y * wv.y;
        ov.z = xv.z * wv.z;
        ov.w = xv.w * wv.w;
        out4[idx] = ov;
    }
}

extern "C" void kernel_launch(void* const* d_in, const int* in_sizes, int n_in,
                              void* d_out, int out_size, void* d_ws, size_t ws_size,
                              hipStream_t stream) {
    const float4* x4 = (const float4*)d_in[0];
    const float4* w4 = (const float4*)d_in[1];
    float4* out4 = (float4*)d_out;

    int n4 = out_size / 4;  // 32768*1024/4 = 8388608
    int block = 256;
    int grid = (n4 + block - 1) / block;  // 32768 blocks
    diag_scale_kernel<<<grid, block, 0, stream>>>(x4, w4, out4, n4);
}